// Round 1
// baseline (409.497 us; speedup 1.0000x reference)
//
#include <hip/hip_runtime.h>
#include <math.h>

#define NUM_CLASSES 27
#define HDIM 256
#define WDIM 256
#define NPIX (HDIM * WDIM)

// ws layout (floats):
//   ws[0]      = entropy sum (over all b,m)
//   ws[1]      = dbc sum (over all b,h,w)
//   ws[8 + b]  = intersection[b]
//   ws[64 + b] = union[b]
// zeroed via hipMemsetAsync each launch.

// ---------------- Kernel 1: per-(b,m) weighted class histogram + entropy ----------------
__global__ __launch_bounds__(512) void hist_entropy_kernel(
    const float* __restrict__ masks, const int* __restrict__ sem,
    float* __restrict__ ws, int M) {
  const int bm = blockIdx.x;
  const int b = bm / M;
  const int m = bm % M;
  const int tid = threadIdx.x;
  const int wave = tid >> 6;

  __shared__ float s_hist[8][28];   // per-wave sub-histograms (+pad)
  __shared__ float s_wsum[8];

  for (int i = tid; i < 8 * 28; i += blockDim.x) ((float*)s_hist)[i] = 0.0f;
  __syncthreads();

  const float4* __restrict__ m4 =
      (const float4*)(masks + ((size_t)b * M + m) * (size_t)NPIX);
  const int4* __restrict__ s4 = (const int4*)(sem + (size_t)b * (size_t)NPIX);

  float msum = 0.0f;
  const int iters = NPIX / 4 / 512;  // 32
#pragma unroll 4
  for (int it = 0; it < iters; ++it) {
    const int idx = it * 512 + tid;
    const float4 mv = m4[idx];
    const int4 cv = s4[idx];
    atomicAdd(&s_hist[wave][cv.x], mv.x);
    atomicAdd(&s_hist[wave][cv.y], mv.y);
    atomicAdd(&s_hist[wave][cv.z], mv.z);
    atomicAdd(&s_hist[wave][cv.w], mv.w);
    msum += mv.x + mv.y + mv.z + mv.w;
  }

  // wave-level reduce of mask sum
  for (int off = 32; off > 0; off >>= 1) msum += __shfl_down(msum, off);
  if ((tid & 63) == 0) s_wsum[wave] = msum;
  __syncthreads();

  if (tid < 64) {
    float ms = s_wsum[0] + s_wsum[1] + s_wsum[2] + s_wsum[3] +
               s_wsum[4] + s_wsum[5] + s_wsum[6] + s_wsum[7] + 1e-6f;
    float ent = 0.0f;  // accumulates p*log(p+1e-10)
    if (tid < NUM_CLASSES) {
      float h = 0.0f;
#pragma unroll
      for (int w = 0; w < 8; ++w) h += s_hist[w][tid];
      float p = h / ms;
      p = fminf(fmaxf(p, 1e-7f), 1.0f);
      if (p > 1e-6f) ent = p * logf(p + 1e-10f);
    }
    for (int off = 32; off > 0; off >>= 1) ent += __shfl_down(ent, off);
    if (tid == 0) atomicAdd(&ws[0], -ent);  // entropy = -sum(...)
  }
}

// ---------------- Kernel 2: boundary IoU + depth-boundary coherence ----------------
__global__ __launch_bounds__(256) void boundary_kernel(
    const int* __restrict__ sem, const float* __restrict__ masks,
    const float* __restrict__ depth, float* __restrict__ ws, int M) {
  // one block per row: blockIdx.x = b*HDIM + y ; threadIdx.x = x
  const int row = blockIdx.x;
  const int b = row / HDIM;
  const int y = row % HDIM;
  const int x = threadIdx.x;

  const size_t base = (size_t)b * NPIX + (size_t)y * WDIM + x;
  const size_t mbase = (size_t)b * M * NPIX + (size_t)y * WDIM + x;  // m=0 slice

  const int   s  = sem[base];
  const float mv = masks[mbase];
  const float dv = depth[base];

  const int   sl = (x > 0) ? sem[base - 1]    : s;
  const float ml = (x > 0) ? masks[mbase - 1] : mv;
  const float dl = (x > 0) ? depth[base - 1]  : dv;

  const int   su = (y > 0) ? sem[base - WDIM]    : s;
  const float mu = (y > 0) ? masks[mbase - WDIM] : mv;
  const float du = (y > 0) ? depth[base - WDIM]  : dv;

  const bool semb  = (s != sl) || (s != su);
  const bool instb = (fabsf(mv - ml) > 0.3f) || (fabsf(mv - mu) > 0.3f);

  float inter = (semb && instb) ? 1.0f : 0.0f;
  float uni   = (semb || instb) ? 1.0f : 0.0f;

  const float dgx = dv - dl;
  const float dgy = dv - du;
  const float ss = dgx * dgx + dgy * dgy;
  const float db = sqrtf(fmaxf(ss, 1e-24f));
  const float dbc = fminf(db, 2.0f);  // clip(db, 0, 2); db >= 0 already
  float term = (1.0f + 3.0f * dbc) * (semb ? 0.0f : 1.0f) * dbc;

  // block reduction of (inter, uni, term)
  const int lane = threadIdx.x & 63;
  const int wave = threadIdx.x >> 6;
  for (int off = 32; off > 0; off >>= 1) {
    inter += __shfl_down(inter, off);
    uni   += __shfl_down(uni, off);
    term  += __shfl_down(term, off);
  }
  __shared__ float s_i[4], s_u[4], s_t[4];
  if (lane == 0) { s_i[wave] = inter; s_u[wave] = uni; s_t[wave] = term; }
  __syncthreads();
  if (threadIdx.x == 0) {
    const float bi = s_i[0] + s_i[1] + s_i[2] + s_i[3];
    const float bu = s_u[0] + s_u[1] + s_u[2] + s_u[3];
    const float bt = s_t[0] + s_t[1] + s_t[2] + s_t[3];
    atomicAdd(&ws[8 + b], bi);
    atomicAdd(&ws[64 + b], bu);
    atomicAdd(&ws[1], bt);
  }
}

// ---------------- Kernel 3: finalize ----------------
__global__ void finalize_kernel(const float* __restrict__ ws,
                                float* __restrict__ out, int B, int M) {
  const float l_u = ws[0] / ((float)(B * M) + 1e-8f);
  float acc = 0.0f;
  for (int b = 0; b < B; ++b) acc += ws[8 + b] / (ws[64 + b] + 1e-8f);
  const float l_b = 1.0f - acc / (float)B;
  const float l_d = ws[1] / (float)((size_t)B * NPIX);
  out[0] = l_u;
  out[1] = l_b;
  out[2] = l_d;
  out[3] = 0.3f * l_u + 0.2f * l_b + 0.2f * l_d;
}

extern "C" void kernel_launch(void* const* d_in, const int* in_sizes, int n_in,
                              void* d_out, int out_size, void* d_ws, size_t ws_size,
                              hipStream_t stream) {
  const int* sem = (const int*)d_in[0];        // (B, N) int32
  const float* masks = (const float*)d_in[1];  // (B, M, N) f32
  const float* depth = (const float*)d_in[2];  // (B, N) f32
  // spatial_h/spatial_w are device scalars; layout is fixed at 256x256 per setup.

  const int B = in_sizes[0] / NPIX;             // 16
  const int M = in_sizes[1] / in_sizes[0];      // 32
  float* ws = (float*)d_ws;
  float* out = (float*)d_out;

  hipMemsetAsync(ws, 0, 128 * sizeof(float), stream);

  hist_entropy_kernel<<<B * M, 512, 0, stream>>>(masks, sem, ws, M);
  boundary_kernel<<<B * HDIM, 256, 0, stream>>>(sem, masks, depth, ws, M);
  finalize_kernel<<<1, 1, 0, stream>>>(ws, out, B, M);
}

// Round 2
// 229.473 us; speedup vs baseline: 1.7845x; 1.7845x over previous
//
#include <hip/hip_runtime.h>
#include <math.h>

#define NUM_CLASSES 27
#define HDIM 256
#define WDIM 256
#define NPIX (HDIM * WDIM)

// ws layout (floats):
//   ws[0]      = entropy sum (over all b,m)
//   ws[1]      = dbc sum (over all b,h,w)
//   ws[8 + b]  = intersection[b]
//   ws[64 + b] = union[b]

// ---------------- Kernel 1: per-(b,m) weighted class histogram + entropy ----------------
// Thread-private 32-word skewed LDS histogram rows; no atomics in the hot loop.
__global__ __launch_bounds__(512) void hist_entropy_kernel(
    const float* __restrict__ masks, const int* __restrict__ sem,
    float* __restrict__ ws, int M) {
  __shared__ float s_hist[512][32];  // 64 KB; row = thread, col = (class+tid)&31
  __shared__ float s_part[16][32];   // stage-2 partials

  const int bm = blockIdx.x;
  const int b = bm / M;
  const int m = bm % M;
  const int tid = threadIdx.x;

  // zero private row (no sync needed: rows are thread-private until merge)
  float4* zr = (float4*)&s_hist[tid][0];
#pragma unroll
  for (int i = 0; i < 8; ++i) zr[i] = make_float4(0.f, 0.f, 0.f, 0.f);

  const float4* __restrict__ m4 =
      (const float4*)(masks + ((size_t)b * M + m) * (size_t)NPIX);
  const int4* __restrict__ s4 = (const int4*)(sem + (size_t)b * (size_t)NPIX);

  float* h = s_hist[tid];
  const int skew = tid & 31;

  const int iters = NPIX / 4 / 512;  // 32
#pragma unroll 4
  for (int it = 0; it < iters; ++it) {
    const int idx = it * 512 + tid;
    const float4 mv = m4[idx];
    const int4 cv = s4[idx];
    h[(cv.x + skew) & 31] += mv.x;
    h[(cv.y + skew) & 31] += mv.y;
    h[(cv.z + skew) & 31] += mv.z;
    h[(cv.w + skew) & 31] += mv.w;
  }
  __syncthreads();

  // stage 2: thread (g = tid>>5, c = tid&31) sums bin c over 32 rows
  {
    const int g = tid >> 5;
    const int c = tid & 31;
    float acc = 0.f;
#pragma unroll
    for (int i = 0; i < 32; ++i) {
      const int r = g * 32 + i;
      acc += s_hist[r][(c + r) & 31];
    }
    s_part[g][c] = acc;
  }
  __syncthreads();

  // stage 3: one wave finishes: total per class, mask_sum = sum of all bins
  if (tid < 64) {
    float tot = 0.f;
    if (tid < 32) {
#pragma unroll
      for (int g = 0; g < 16; ++g) tot += s_part[g][tid];  // bins 27..31 are 0
    }
    float ms = tot;
    for (int off = 32; off > 0; off >>= 1) ms += __shfl_xor(ms, off);
    ms += 1e-6f;  // mask_sum = sum over all n (+eps), since every n maps to one bin
    float ent = 0.f;
    if (tid < NUM_CLASSES) {
      float p = fminf(fmaxf(tot / ms, 1e-7f), 1.0f);
      if (p > 1e-6f) ent = p * logf(p + 1e-10f);
    }
    for (int off = 32; off > 0; off >>= 1) ent += __shfl_xor(ent, off);
    if (tid == 0) atomicAdd(&ws[0], -ent);
  }
}

// ---------------- Kernel 2: boundary IoU + depth-boundary coherence ----------------
// One wave per image row (64 lanes x float4 = 256 px); 4 rows per block.
__global__ __launch_bounds__(256) void boundary_kernel(
    const int* __restrict__ sem, const float* __restrict__ masks,
    const float* __restrict__ depth, float* __restrict__ ws, int M) {
  const int wave = threadIdx.x >> 6;
  const int lane = threadIdx.x & 63;
  const int brow = blockIdx.x * 4 + wave;  // global row index in [0, B*HDIM)
  const int b = brow >> 8;                 // HDIM == 256
  const int y = brow & 255;

  const size_t rowoff = (size_t)b * NPIX + (size_t)y * WDIM;
  const float4* mp = (const float4*)(masks + (size_t)b * M * NPIX + (size_t)y * WDIM);
  const float4* dp = (const float4*)(depth + rowoff);
  const int4* sp = (const int4*)(sem + rowoff);

  const int uoff = (y > 0) ? -(WDIM / 4) : 0;  // up-row offset in vec4 units

  const float4 mv = mp[lane];
  const float4 mvu = mp[lane + uoff];
  const float4 dv = dp[lane];
  const float4 dvu = dp[lane + uoff];
  const int4 sv = sp[lane];
  const int4 svu = sp[lane + uoff];

  // left neighbors of element .x come from previous lane's .w (edge: own .x)
  const int src = (lane > 0) ? (lane - 1) : 0;
  float mw = __shfl(mv.w, src);
  float dw = __shfl(dv.w, src);
  int swv = __shfl(sv.w, src);
  if (lane == 0) { mw = mv.x; dw = dv.x; swv = sv.x; }

  const float ml[4] = {mw, mv.x, mv.y, mv.z};
  const float dl[4] = {dw, dv.x, dv.y, dv.z};
  const int sl[4] = {swv, sv.x, sv.y, sv.z};
  const float mc[4] = {mv.x, mv.y, mv.z, mv.w};
  const float dc[4] = {dv.x, dv.y, dv.z, dv.w};
  const int sc[4] = {sv.x, sv.y, sv.z, sv.w};
  const float mu[4] = {mvu.x, mvu.y, mvu.z, mvu.w};
  const float du[4] = {dvu.x, dvu.y, dvu.z, dvu.w};
  const int su[4] = {svu.x, svu.y, svu.z, svu.w};

  float inter = 0.f, uni = 0.f, term = 0.f;
#pragma unroll
  for (int j = 0; j < 4; ++j) {
    const bool semb = (sc[j] != sl[j]) || (sc[j] != su[j]);
    const bool instb = (fabsf(mc[j] - ml[j]) > 0.3f) || (fabsf(mc[j] - mu[j]) > 0.3f);
    inter += (semb && instb) ? 1.0f : 0.0f;
    uni += (semb || instb) ? 1.0f : 0.0f;
    const float gx = dc[j] - dl[j];
    const float gy = dc[j] - du[j];
    const float db = sqrtf(fmaxf(gx * gx + gy * gy, 1e-24f));
    const float dbc = fminf(db, 2.0f);
    term += semb ? 0.0f : (1.0f + 3.0f * dbc) * dbc;
  }

  for (int off = 32; off > 0; off >>= 1) {
    inter += __shfl_down(inter, off);
    uni += __shfl_down(uni, off);
    term += __shfl_down(term, off);
  }
  __shared__ float s_i[4], s_u[4], s_t[4];
  if (lane == 0) { s_i[wave] = inter; s_u[wave] = uni; s_t[wave] = term; }
  __syncthreads();
  if (threadIdx.x == 0) {
    const float bi = s_i[0] + s_i[1] + s_i[2] + s_i[3];
    const float bu = s_u[0] + s_u[1] + s_u[2] + s_u[3];
    const float bt = s_t[0] + s_t[1] + s_t[2] + s_t[3];
    atomicAdd(&ws[8 + b], bi);   // all 4 rows in a block share b (256 % 4 == 0)
    atomicAdd(&ws[64 + b], bu);
    atomicAdd(&ws[1], bt);
  }
}

// ---------------- Kernel 3: finalize ----------------
__global__ void finalize_kernel(const float* __restrict__ ws,
                                float* __restrict__ out, int B, int M) {
  const float l_u = ws[0] / ((float)(B * M) + 1e-8f);
  float acc = 0.0f;
  for (int b = 0; b < B; ++b) acc += ws[8 + b] / (ws[64 + b] + 1e-8f);
  const float l_b = 1.0f - acc / (float)B;
  const float l_d = ws[1] / (float)((size_t)B * NPIX);
  out[0] = l_u;
  out[1] = l_b;
  out[2] = l_d;
  out[3] = 0.3f * l_u + 0.2f * l_b + 0.2f * l_d;
}

extern "C" void kernel_launch(void* const* d_in, const int* in_sizes, int n_in,
                              void* d_out, int out_size, void* d_ws, size_t ws_size,
                              hipStream_t stream) {
  const int* sem = (const int*)d_in[0];        // (B, N) int32
  const float* masks = (const float*)d_in[1];  // (B, M, N) f32
  const float* depth = (const float*)d_in[2];  // (B, N) f32

  const int B = in_sizes[0] / NPIX;         // 16
  const int M = in_sizes[1] / in_sizes[0];  // 32
  float* ws = (float*)d_ws;
  float* out = (float*)d_out;

  hipMemsetAsync(ws, 0, 128 * sizeof(float), stream);

  hist_entropy_kernel<<<B * M, 512, 0, stream>>>(masks, sem, ws, M);
  boundary_kernel<<<B * HDIM / 4, 256, 0, stream>>>(sem, masks, depth, ws, M);
  finalize_kernel<<<1, 1, 0, stream>>>(ws, out, B, M);
}

// Round 3
// 202.813 us; speedup vs baseline: 2.0191x; 1.1315x over previous
//
#include <hip/hip_runtime.h>
#include <math.h>

#define NUM_CLASSES 27
#define HDIM 256
#define WDIM 256
#define NPIX (HDIM * WDIM)

// Fixed problem shape: B=16, M=32, H=W=256.
#define NB_HIST 512              // B*M blocks, one per (b,m)
#define NB_BND 512               // B*HDIM/8 blocks, 8 rows each
#define ROWS_PER_BND_BLOCK 8

// ws layout (floats), all slots written every launch (no zeroing needed):
//   ws[0    .. 512)  : entropy per (b,m) block
//   ws[512  .. 1024) : intersection per boundary block
//   ws[1024 .. 1536) : union per boundary block
//   ws[1536 .. 2048) : dbc-term sum per boundary block

__global__ __launch_bounds__(512) void fused_kernel(
    const float* __restrict__ masks, const int* __restrict__ sem,
    const float* __restrict__ depth, float* __restrict__ ws, int M) {
  // Conflict-free layout: bin c of thread t at s_hist[c][t].
  // Row stride = 512 floats (== 0 mod 32 banks), so bank = t & 31:
  // class-independent, exactly 2 lanes/bank per wave access -> free (m136).
  __shared__ float s_hist[28][512];  // 57 KB
  __shared__ float s_part[16][32];
  __shared__ float s_i[8], s_u[8], s_t[8];

  const int tid = threadIdx.x;

  if (blockIdx.x < NB_HIST) {
    // ---------------- histogram + entropy for one (b,m) ----------------
    const int bm = blockIdx.x;
    const int b = bm / M;
    const int m = bm % M;

    float* col = &s_hist[0][tid];  // bin c at col[c*512]
#pragma unroll
    for (int c = 0; c < 28; ++c) col[c * 512] = 0.0f;
    // no sync needed: hot loop touches only this thread's own column

    const float4* __restrict__ m4 =
        (const float4*)(masks + ((size_t)b * M + m) * (size_t)NPIX);
    const int4* __restrict__ s4 = (const int4*)(sem + (size_t)b * (size_t)NPIX);

    const int iters = NPIX / 4 / 512;  // 32
#pragma unroll 4
    for (int it = 0; it < iters; ++it) {
      const int idx = it * 512 + tid;
      const float4 mv = m4[idx];
      const int4 cv = s4[idx];
      col[cv.x * 512] += mv.x;
      col[cv.y * 512] += mv.y;
      col[cv.z * 512] += mv.z;
      col[cv.w * 512] += mv.w;
    }
    __syncthreads();

    // stage 2: thread (c = tid&31, s = tid>>5) sums bin c over 32 columns.
    // Skew iteration by c so banks stay spread (2-way only).
    {
      const int c = tid & 31;
      const int s = tid >> 5;
      if (c < 28) {
        float acc = 0.f;
#pragma unroll
        for (int i = 0; i < 32; ++i)
          acc += s_hist[c][s * 32 + ((i + c) & 31)];
        s_part[s][c] = acc;
      }
    }
    __syncthreads();

    // stage 3: one wave finishes
    if (tid < 64) {
      float tot = 0.f;
      if (tid < 28) {
#pragma unroll
        for (int g = 0; g < 16; ++g) tot += s_part[g][tid];
      }
      float ms = tot;  // sum of all bins == sum over n of mask
      for (int off = 32; off > 0; off >>= 1) ms += __shfl_xor(ms, off);
      ms += 1e-6f;
      float ent = 0.f;
      if (tid < NUM_CLASSES) {
        float p = fminf(fmaxf(tot / ms, 1e-7f), 1.0f);
        if (p > 1e-6f) ent = p * logf(p + 1e-10f);
      }
      for (int off = 32; off > 0; off >>= 1) ent += __shfl_xor(ent, off);
      if (tid == 0) ws[bm] = -ent;
    }
  } else {
    // ---------------- boundary IoU + depth coherence: 8 rows/block ----------------
    const int j = blockIdx.x - NB_HIST;
    const int wave = tid >> 6;
    const int lane = tid & 63;
    const int brow = j * ROWS_PER_BND_BLOCK + wave;  // all 8 rows share b
    const int b = brow >> 8;
    const int y = brow & 255;

    const size_t rowoff = (size_t)b * NPIX + (size_t)y * WDIM;
    const float4* mp = (const float4*)(masks + (size_t)b * M * NPIX + (size_t)y * WDIM);
    const float4* dp = (const float4*)(depth + rowoff);
    const int4* sp = (const int4*)(sem + rowoff);

    const int uoff = (y > 0) ? -(WDIM / 4) : 0;

    const float4 mv = mp[lane];
    const float4 mvu = mp[lane + uoff];
    const float4 dv = dp[lane];
    const float4 dvu = dp[lane + uoff];
    const int4 sv = sp[lane];
    const int4 svu = sp[lane + uoff];

    const int src = (lane > 0) ? (lane - 1) : 0;
    float mw = __shfl(mv.w, src);
    float dw = __shfl(dv.w, src);
    int swv = __shfl(sv.w, src);
    if (lane == 0) { mw = mv.x; dw = dv.x; swv = sv.x; }

    const float ml[4] = {mw, mv.x, mv.y, mv.z};
    const float dl[4] = {dw, dv.x, dv.y, dv.z};
    const int sl[4] = {swv, sv.x, sv.y, sv.z};
    const float mc[4] = {mv.x, mv.y, mv.z, mv.w};
    const float dc[4] = {dv.x, dv.y, dv.z, dv.w};
    const int sc[4] = {sv.x, sv.y, sv.z, sv.w};
    const float mu[4] = {mvu.x, mvu.y, mvu.z, mvu.w};
    const float du[4] = {dvu.x, dvu.y, dvu.z, dvu.w};
    const int su[4] = {svu.x, svu.y, svu.z, svu.w};

    float inter = 0.f, uni = 0.f, term = 0.f;
#pragma unroll
    for (int k = 0; k < 4; ++k) {
      const bool semb = (sc[k] != sl[k]) || (sc[k] != su[k]);
      const bool instb = (fabsf(mc[k] - ml[k]) > 0.3f) || (fabsf(mc[k] - mu[k]) > 0.3f);
      inter += (semb && instb) ? 1.0f : 0.0f;
      uni += (semb || instb) ? 1.0f : 0.0f;
      const float gx = dc[k] - dl[k];
      const float gy = dc[k] - du[k];
      const float db = sqrtf(fmaxf(gx * gx + gy * gy, 1e-24f));
      const float dbc = fminf(db, 2.0f);
      term += semb ? 0.0f : (1.0f + 3.0f * dbc) * dbc;
    }

    for (int off = 32; off > 0; off >>= 1) {
      inter += __shfl_down(inter, off);
      uni += __shfl_down(uni, off);
      term += __shfl_down(term, off);
    }
    if (lane == 0) { s_i[wave] = inter; s_u[wave] = uni; s_t[wave] = term; }
    __syncthreads();
    if (tid == 0) {
      float bi = 0.f, bu = 0.f, bt = 0.f;
#pragma unroll
      for (int w = 0; w < 8; ++w) { bi += s_i[w]; bu += s_u[w]; bt += s_t[w]; }
      ws[512 + j] = bi;
      ws[1024 + j] = bu;
      ws[1536 + j] = bt;
    }
  }
}

// ---------------- finalize: reduce all per-block partials ----------------
__global__ __launch_bounds__(512) void finalize_kernel(
    const float* __restrict__ ws, float* __restrict__ out, int B, int M) {
  const int tid = threadIdx.x;
  const int lane = tid & 63;
  const int wave = tid >> 6;
  __shared__ float s_e[8], s_d[8], s_r[16];

  float e = ws[tid];            // entropy partials (512)
  float dbc = ws[1536 + tid];   // dbc partials (512)
  float inter = ws[512 + tid];  // per-boundary-block inter
  float uni = ws[1024 + tid];   // per-boundary-block union

  // per-b IoU: boundary blocks of image b are tid in [32b, 32b+32)
  for (int off = 16; off > 0; off >>= 1) {
    inter += __shfl_down(inter, off, 32);
    uni += __shfl_down(uni, off, 32);
  }
  if ((tid & 31) == 0) s_r[tid >> 5] = inter / (uni + 1e-8f);

  for (int off = 32; off > 0; off >>= 1) {
    e += __shfl_down(e, off);
    dbc += __shfl_down(dbc, off);
  }
  if (lane == 0) { s_e[wave] = e; s_d[wave] = dbc; }
  __syncthreads();

  if (tid == 0) {
    float se = 0.f, sd = 0.f, sr = 0.f;
#pragma unroll
    for (int w = 0; w < 8; ++w) { se += s_e[w]; sd += s_d[w]; }
#pragma unroll
    for (int b = 0; b < 16; ++b) sr += s_r[b];
    const float l_u = se / ((float)(B * M) + 1e-8f);
    const float l_b = 1.0f - sr / (float)B;
    const float l_d = sd / (float)((size_t)B * NPIX);
    out[0] = l_u;
    out[1] = l_b;
    out[2] = l_d;
    out[3] = 0.3f * l_u + 0.2f * l_b + 0.2f * l_d;
  }
}

extern "C" void kernel_launch(void* const* d_in, const int* in_sizes, int n_in,
                              void* d_out, int out_size, void* d_ws, size_t ws_size,
                              hipStream_t stream) {
  const int* sem = (const int*)d_in[0];        // (B, N) int32
  const float* masks = (const float*)d_in[1];  // (B, M, N) f32
  const float* depth = (const float*)d_in[2];  // (B, N) f32

  const int B = in_sizes[0] / NPIX;         // 16
  const int M = in_sizes[1] / in_sizes[0];  // 32
  float* ws = (float*)d_ws;
  float* out = (float*)d_out;

  fused_kernel<<<NB_HIST + NB_BND, 512, 0, stream>>>(masks, sem, depth, ws, M);
  finalize_kernel<<<1, 512, 0, stream>>>(ws, out, B, M);
}